// Round 1
// baseline (1215.324 us; speedup 1.0000x reference)
//
#include <hip/hip_runtime.h>
#include <cstdint>
#include <cstddef>

// B=32 T=49 N=24 H=128 G=9 ; R=B*N=768 ; concat K = 768
// d_out element offsets (fp32)
#define OUT_CH   4816896
#define OUT_GT   9633792
#define OUT_CGT  9732096
#define OUT_GS   9830400
#define OUT_CGS 10031104

typedef __attribute__((ext_vector_type(8))) short bf16x8;
typedef __attribute__((ext_vector_type(4))) float f32x4;

#define DEV static __device__ __forceinline__

DEV short f2bf(float f){
  union{float f; uint32_t u;} v; v.f=f;
  uint32_t r = v.u + 0x7fffu + ((v.u>>16)&1u);
  return (short)(r>>16);
}
DEV float bf2f(short s){
  union{uint32_t u; float f;} v; v.u = ((uint32_t)(uint16_t)s)<<16; return v.f;
}
DEV float sigm(float x){ return 1.0f/(1.0f + __expf(-x)); }
DEV float tanh_(float x){ return 2.0f/(1.0f + __expf(-2.0f*x)) - 1.0f; }

#define GLD16(gp, lp) __builtin_amdgcn_global_load_lds( \
    (const __attribute__((address_space(1))) unsigned int*)(gp), \
    (__attribute__((address_space(3))) unsigned int*)(lp), 16, 0, 0)

// ---------------------------------------------------------------------------
// 1. Weight transpose + bf16 cast.
//    blocks 0..2645: WB[t][g][kout 128][kin 768]  from U|Wt(3 chunks)|Ws|Zt
//    blocks 2646..2792: WgtT[j*49+t][128][128]
//    blocks 2793..2939: ZgtT[j*49+t][128][128]
__global__ __launch_bounds__(256) void k_prep(
    const float* __restrict__ U,  const float* __restrict__ Wt,
    const float* __restrict__ Ws, const float* __restrict__ Zt,
    const float* __restrict__ Wgt,const float* __restrict__ Zgt,
    short* __restrict__ WB, short* __restrict__ WgtT, short* __restrict__ ZgtT)
{
  __shared__ float tile[128*129];
  int bid = blockIdx.x, tid = threadIdx.x;
  const float* src; short* dst; int dstStride;
  if (bid < 2646){
    int c6 = bid % 6; int gt = bid / 6; int g = gt/49, t = gt%49;
    int gtH = g*49 + t;
    if (c6==0)      src = U  + (size_t)gtH*16384;
    else if (c6<=3) src = Wt + ((size_t)gtH*384 + (size_t)(c6-1)*128)*128;
    else if (c6==4) src = Ws + (size_t)gtH*16384;
    else            src = Zt + (size_t)gtH*16384;
    dst = WB + (size_t)(t*9+g)*128*768 + c6*128;
    dstStride = 768;
  } else if (bid < 2793){
    int i = bid - 2646;           // j*49+t
    src = Wgt + (size_t)i*16384;  dst = WgtT + (size_t)i*16384; dstStride = 128;
  } else {
    int i = bid - 2793;
    src = Zgt + (size_t)i*16384;  dst = ZgtT + (size_t)i*16384; dstStride = 128;
  }
  for (int it=0; it<64; ++it){               // load 128x128 fp32, padded LDS
    int idx = it*256 + tid;
    int r = idx >> 7, c = idx & 127;
    tile[r*129 + c] = src[idx];
  }
  __syncthreads();
  for (int it=0; it<32; ++it){               // write transposed bf16, short2
    int idx = it*256 + tid;                  // pair index
    int ko = idx >> 6;
    int ki = (idx & 63)*2;
    short2 v;
    v.x = f2bf(tile[(size_t)ki*129 + ko]);
    v.y = f2bf(tile[(size_t)(ki+1)*129 + ko]);
    *(short2*)&dst[(size_t)ko*dstStride + ki] = v;
  }
}

// ---------------------------------------------------------------------------
// 2. x_cat build: XC[t][r=b*24+n][768] bf16 = [h | h_{t-1} | p | h_{t+1} | x_s | g_t]
__global__ __launch_bounds__(256) void k_xc(
    const float* __restrict__ h, const float* __restrict__ p,
    const float* __restrict__ gt_in, short* __restrict__ XC)
{
  int bid = blockIdx.x, tid = threadIdx.x;
  int b = bid / 49, t = bid % 49;
  const size_t bt = ((size_t)b*49 + t)*24*128;
  for (int it=0; it<36; ++it){
    int idx = (it*256 + tid)*2;              // even element index, 0..18430
    int n = idx / 768; int kk = idx - n*768;
    int seg = kk >> 7; int k = kk & 127;
    size_t nk = (size_t)n*128 + k;
    float vx=0.f, vy=0.f;
    if (seg==0){ float2 u = *(const float2*)&h[bt + nk]; vx=u.x; vy=u.y; }
    else if (seg==1){ if (t>0){ float2 u = *(const float2*)&h[bt - 3072 + nk]; vx=u.x; vy=u.y; } }
    else if (seg==2){ float2 u = *(const float2*)&p[bt + nk]; vx=u.x; vy=u.y; }
    else if (seg==3){ if (t<48){ float2 u = *(const float2*)&h[bt + 3072 + nk]; vx=u.x; vy=u.y; } }
    else if (seg==4){
      if (n>0){ float2 u = *(const float2*)&h[bt + nk - 128]; vx+=u.x; vy+=u.y; }
      if (n<23){ float2 u = *(const float2*)&h[bt + nk + 128]; vx+=u.x; vy+=u.y; }
    } else {
      float2 u = *(const float2*)&gt_in[((size_t)b*24 + n)*128 + k]; vx=u.x; vy=u.y;
    }
    short2 s2; s2.x = f2bf(vx); s2.y = f2bf(vy);
    *(short2*)&XC[((size_t)t*768 + b*24 + n)*768 + kk] = s2;
  }
}

// ---------------------------------------------------------------------------
// 3. bias2[g][t][b][k] = b[g,t,k] + sum_h g_s[b,t,h]*Zs[g,t,h,k]
__global__ __launch_bounds__(256) void k_bias2(
    const float* __restrict__ gs_in, const float* __restrict__ Zs,
    const float* __restrict__ bvec, float* __restrict__ bias2)
{
  __shared__ float gsL[32*128];
  int bid = blockIdx.x, tid = threadIdx.x;
  int g = bid / 49, t = bid % 49;
  for (int i=0;i<16;++i){
    int idx = i*256 + tid; int bb = idx>>7, kk = idx&127;
    gsL[idx] = gs_in[((size_t)bb*49 + t)*128 + kk];
  }
  __syncthreads();
  int k = tid & 127, half = tid >> 7;
  float acc[16];
  #pragma unroll
  for (int i=0;i<16;++i) acc[i]=0.f;
  const float* Zb = Zs + (size_t)(g*49+t)*16384;
  for (int hc=0; hc<16; ++hc){
    float z[8];
    #pragma unroll
    for (int jj=0;jj<8;++jj) z[jj] = Zb[(size_t)(hc*8+jj)*128 + k];
    #pragma unroll
    for (int bb=0; bb<16; ++bb){
      const float* gp = &gsL[(half*16+bb)*128 + hc*8];
      #pragma unroll
      for (int jj=0;jj<8;++jj) acc[bb] += gp[jj]*z[jj];
    }
  }
  float bv = bvec[(size_t)(g*49+t)*128 + k];
  #pragma unroll
  for (int bb=0; bb<16; ++bb)
    bias2[((size_t)(g*49+t)*32 + half*16+bb)*128 + k] = acc[bb] + bv;
}

// ---------------------------------------------------------------------------
// 4. Main GEMM: pre[g][t][r][k] (bf16) = XC[t] (768x768) @ WB[t][g]^T + bias2
//    m97-style: 128x128 tile, BK=64, 4 waves, global_load_lds 16B.
__global__ __launch_bounds__(256) void k_gemm_main(
    const short* __restrict__ XC, const short* __restrict__ WB,
    const float* __restrict__ bias2, short* __restrict__ preB)
{
  __shared__ short As[128*64];
  __shared__ short Bs[128*64];
  int bid = blockIdx.x, tid = threadIdx.x;
  int m = bid % 6; int gt = bid / 6; int g = gt/49, t = gt%49;
  const int lane = tid & 63, w = tid >> 6;
  const int wm = w >> 1, wn = w & 1;
  const int lr = lane & 15, lk = lane >> 4;
  const short* Abase = XC + ((size_t)t*768 + m*128)*768;
  const short* Bbase = WB + (size_t)(t*9+g)*128*768;
  f32x4 acc[4][4] = {};
  for (int kt=0; kt<12; ++kt){
    int kofs = kt*64;
    #pragma unroll
    for (int it=0; it<4; ++it){
      int fb = it*4096 + tid*16;             // byte offset in 16KB tile
      int row = fb >> 7;
      int col = (fb & 127) >> 1;             // bf16 col 0..63
      GLD16(Abase + (size_t)row*768 + kofs + col, (char*)As + fb);
      GLD16(Bbase + (size_t)row*768 + kofs + col, (char*)Bs + fb);
    }
    __syncthreads();
    bf16x8 a[4][2], bb[4][2];
    #pragma unroll
    for (int mf=0; mf<4; ++mf)
      #pragma unroll
      for (int ks=0; ks<2; ++ks)
        a[mf][ks] = *(const bf16x8*)&As[(wm*64 + mf*16 + lr)*64 + ks*32 + lk*8];
    #pragma unroll
    for (int nf=0; nf<4; ++nf)
      #pragma unroll
      for (int ks=0; ks<2; ++ks)
        bb[nf][ks] = *(const bf16x8*)&Bs[(wn*64 + nf*16 + lr)*64 + ks*32 + lk*8];
    #pragma unroll
    for (int mf=0; mf<4; ++mf)
      #pragma unroll
      for (int nf=0; nf<4; ++nf)
        #pragma unroll
        for (int ks=0; ks<2; ++ks)
          acc[mf][nf] = __builtin_amdgcn_mfma_f32_16x16x32_bf16(a[mf][ks], bb[nf][ks], acc[mf][nf], 0,0,0);
    __syncthreads();
  }
  const size_t preBase = ((size_t)g*49 + t)*768*128;
  const size_t b2Base  = ((size_t)g*49 + t)*32*128;
  #pragma unroll
  for (int mf=0; mf<4; ++mf){
    #pragma unroll
    for (int nf=0; nf<4; ++nf){
      int kout = wn*64 + nf*16 + lr;
      #pragma unroll
      for (int reg=0; reg<4; ++reg){
        int gr = m*128 + wm*64 + mf*16 + lk*4 + reg;   // global row (b*24+n)
        int bb2 = (gr*2731) >> 16;                     // gr/24
        float v = acc[mf][nf][reg] + bias2[b2Base + (size_t)bb2*128 + kout];
        preB[preBase + (size_t)gr*128 + kout] = f2bf(v);
      }
    }
  }
}

// ---------------------------------------------------------------------------
// 5. Elementwise gate combine -> h_new, c_h_new (d_out) + hnb (bf16 copy)
__global__ __launch_bounds__(256) void k_stageb(
    const short* __restrict__ preB, const float* __restrict__ c_h,
    const float* __restrict__ c_gt, const float* __restrict__ c_gs,
    float* __restrict__ out, short* __restrict__ hnb)
{
  int bid = blockIdx.x, tid = threadIdx.x;
  int ng = bid % 6; int bt = bid / 6; int b = bt/49, t = bt%49;
  int nl = tid >> 6; int n = ng*4 + nl; int k = (tid & 63)*2;
  int r = b*24 + n;
  size_t btn = ((size_t)b*49 + t)*3072 + (size_t)n*128 + k;
  float pg[9][2];
  #pragma unroll
  for (int g=0; g<9; ++g){
    short2 s = *(const short2*)&preB[((size_t)g*49 + t)*98304 + (size_t)r*128 + k];
    pg[g][0] = bf2f(s.x); pg[g][1] = bf2f(s.y);
  }
  float cct[2], ctb[2]={0,0}, cta[2]={0,0}, cs[2]={0,0}, cgt[2], cgs[2];
  { float2 v = *(const float2*)&c_h[btn]; cct[0]=v.x; cct[1]=v.y; }
  if (t>0){ float2 v = *(const float2*)&c_h[btn - 3072]; ctb[0]=v.x; ctb[1]=v.y; }
  if (t<48){ float2 v = *(const float2*)&c_h[btn + 3072]; cta[0]=v.x; cta[1]=v.y; }
  if (n>0){ float2 v = *(const float2*)&c_h[btn - 128]; cs[0]+=v.x; cs[1]+=v.y; }
  if (n<23){ float2 v = *(const float2*)&c_h[btn + 128]; cs[0]+=v.x; cs[1]+=v.y; }
  { float2 v = *(const float2*)&c_gt[(size_t)r*128 + k]; cgt[0]=v.x; cgt[1]=v.y; }
  { float2 v = *(const float2*)&c_gs[((size_t)b*49 + t)*128 + k]; cgs[0]=v.x; cgs[1]=v.y; }
  float hn[2], cn[2];
  #pragma unroll
  for (int e=0; e<2; ++e){
    float gi = sigm(pg[0][e]), lt = sigm(pg[1][e]), ft = sigm(pg[2][e]), rt = sigm(pg[3][e]);
    float sg = sigm(pg[4][e]), gtg = sigm(pg[5][e]), gsg = sigm(pg[6][e]), o = sigm(pg[7][e]);
    float cc = tanh_(pg[8][e]);
    cn[e] = lt*ctb[e] + ft*cct[e] + rt*cta[e] + sg*cs[e] + gtg*cgt[e] + gsg*cgs[e] + gi*cc;
    hn[e] = o * tanh_(cn[e]);
  }
  float2 v1; v1.x = hn[0]; v1.y = hn[1];
  *(float2*)&out[btn] = v1;
  v1.x = cn[0]; v1.y = cn[1];
  *(float2*)&out[OUT_CH + btn] = v1;
  short2 s2; s2.x = f2bf(hn[0]); s2.y = f2bf(hn[1]);
  *(short2*)&hnb[((size_t)t*768 + r)*128 + k] = s2;
}

// ---------------------------------------------------------------------------
// 6. hm[b,t,k] = mean_n h_new
__global__ __launch_bounds__(128) void k_hm(const float* __restrict__ out, float* __restrict__ hm)
{
  int bid = blockIdx.x; int b = bid/49, t = bid%49; int k = threadIdx.x;
  float s = 0.f;
  for (int n=0;n<24;++n) s += out[((size_t)(b*49+t)*24 + n)*128 + k];
  hm[(size_t)(b*49+t)*128 + k] = s * (1.0f/24.0f);
}

// ---------------------------------------------------------------------------
// 7. Agt[t][j][r][k] = h_new[t] @ Wgt[j,t] + bgt[j,t]   (fp32 out)
__global__ __launch_bounds__(256) void k_gemm_agt(
    const short* __restrict__ hnb, const short* __restrict__ WgtT,
    const float* __restrict__ bgt, float* __restrict__ Agt)
{
  __shared__ short As[128*64];
  __shared__ short Bs[128*64];
  int bid = blockIdx.x, tid = threadIdx.x;
  int m = bid % 6; int jt = bid / 6; int j = jt/49, t = jt%49;
  const int lane = tid & 63, w = tid >> 6;
  const int wm = w >> 1, wn = w & 1;
  const int lr = lane & 15, lk = lane >> 4;
  const short* Abase = hnb + ((size_t)t*768 + m*128)*128;
  const short* Bbase = WgtT + (size_t)(j*49+t)*16384;
  f32x4 acc[4][4] = {};
  for (int kt=0; kt<2; ++kt){
    int kofs = kt*64;
    #pragma unroll
    for (int it=0; it<4; ++it){
      int fb = it*4096 + tid*16;
      int row = fb >> 7;
      int col = (fb & 127) >> 1;
      GLD16(Abase + (size_t)row*128 + kofs + col, (char*)As + fb);
      GLD16(Bbase + (size_t)row*128 + kofs + col, (char*)Bs + fb);
    }
    __syncthreads();
    bf16x8 a[4][2], bb[4][2];
    #pragma unroll
    for (int mf=0; mf<4; ++mf)
      #pragma unroll
      for (int ks=0; ks<2; ++ks)
        a[mf][ks] = *(const bf16x8*)&As[(wm*64 + mf*16 + lr)*64 + ks*32 + lk*8];
    #pragma unroll
    for (int nf=0; nf<4; ++nf)
      #pragma unroll
      for (int ks=0; ks<2; ++ks)
        bb[nf][ks] = *(const bf16x8*)&Bs[(wn*64 + nf*16 + lr)*64 + ks*32 + lk*8];
    #pragma unroll
    for (int mf=0; mf<4; ++mf)
      #pragma unroll
      for (int nf=0; nf<4; ++nf)
        #pragma unroll
        for (int ks=0; ks<2; ++ks)
          acc[mf][nf] = __builtin_amdgcn_mfma_f32_16x16x32_bf16(a[mf][ks], bb[nf][ks], acc[mf][nf], 0,0,0);
    __syncthreads();
  }
  #pragma unroll
  for (int mf=0; mf<4; ++mf){
    #pragma unroll
    for (int nf=0; nf<4; ++nf){
      int kout = wn*64 + nf*16 + lr;
      #pragma unroll
      for (int reg=0; reg<4; ++reg){
        int gr = m*128 + wm*64 + mf*16 + lk*4 + reg;
        Agt[((size_t)t*3 + j)*98304 + (size_t)gr*128 + kout] =
            acc[mf][nf][reg] + bgt[(size_t)(j*49+t)*128 + kout];
      }
    }
  }
}

// ---------------------------------------------------------------------------
// 8. g_s path (parallel over t,b)
__global__ __launch_bounds__(256) void k_gs(
    const float* __restrict__ hm, const float* __restrict__ gs_in,
    const float* __restrict__ cgs_in,
    const float* __restrict__ Wgs, const float* __restrict__ Zgs,
    const float* __restrict__ bgs, float* __restrict__ out)
{
  __shared__ float hmL[2][128], gsL[2][128];
  int bid = blockIdx.x, tid = threadIdx.x;
  int t = bid / 16; int bp = bid % 16;
  int bsel = tid >> 7; int k = tid & 127;
  int b = bp*2 + bsel;
  {
    int bs = tid >> 7, kk = tid & 127;
    hmL[bs][kk] = hm[((size_t)(bp*2+bs)*49 + t)*128 + kk];
    gsL[bs][kk] = gs_in[((size_t)(bp*2+bs)*49 + t)*128 + kk];
  }
  __syncthreads();
  const float* W0 = Wgs + (size_t)t*16384;
  const float* W1 = Wgs + (size_t)(49+t)*16384;
  const float* W2 = Wgs + (size_t)(98+t)*16384;
  const float* Z0 = Zgs + (size_t)t*16384;
  const float* Z1 = Zgs + (size_t)(49+t)*16384;
  const float* Z2 = Zgs + (size_t)(98+t)*16384;
  float accf=0.f, accg=0.f, acco=0.f;
  for (int h=0; h<128; ++h){
    float hv = hmL[bsel][h], gv = gsL[bsel][h];
    accf += hv*W0[(size_t)h*128+k] + gv*Z0[(size_t)h*128+k];
    accg += hv*W1[(size_t)h*128+k] + gv*Z1[(size_t)h*128+k];
    acco += hv*W2[(size_t)h*128+k] + gv*Z2[(size_t)h*128+k];
  }
  float f  = sigm(accf + bgs[(size_t)t*128 + k]);
  float gc = tanh_(accg + bgs[(size_t)(49+t)*128 + k]);
  float og = sigm(acco + bgs[(size_t)(98+t)*128 + k]);
  float cg = cgs_in[((size_t)b*49 + t)*128 + k];
  float cn = f*cg + (1.0f-f)*gc;
  out[OUT_CGS + ((size_t)b*49+t)*128 + k] = cn;
  out[OUT_GS  + ((size_t)b*49+t)*128 + k] = og * tanh_(cn);
}

// ---------------------------------------------------------------------------
// 9. g_t recurrence: 48 blocks x 16 rows, 49 sequential steps.
//    pre = Agt[t] + g @ Zgt[t]  (MFMA M=16, N=384, K=128)
__global__ __launch_bounds__(256) void k_recur(
    const float* __restrict__ Agt, const short* __restrict__ ZgtT,
    const float* __restrict__ gt_in, const float* __restrict__ cgt_in,
    float* __restrict__ out)
{
  __shared__ short gA[16*128];      // bf16 g, XOR-swizzled rows
  __shared__ float preL[16*384];
  int bid = blockIdx.x, tid = threadIdx.x;
  const int rowbase = bid*16;
  const int lane = tid & 63, w = tid >> 6;
  const int lr = lane & 15, lk = lane >> 4;
  const int k = tid & 127, rh = tid >> 7;

  float c[8];
  #pragma unroll
  for (int rr=0; rr<8; ++rr){
    int row = rh*8 + rr; int r = rowbase + row;
    c[rr] = cgt_in[(size_t)r*128 + k];
    float gv = gt_in[(size_t)r*128 + k];
    int byte = (row*256 + k*2) ^ ((row&7)<<4);
    *(short*)((char*)gA + byte) = f2bf(gv);
  }
  __syncthreads();

  for (int t=0; t<49; ++t){
    bf16x8 a[4];
    #pragma unroll
    for (int ks=0; ks<4; ++ks){
      int byte = (lr*256 + ks*64 + lk*16) ^ ((lr&7)<<4);
      a[ks] = *(const bf16x8*)((const char*)gA + byte);
    }
    f32x4 acc[6] = {};
    #pragma unroll
    for (int nf=0; nf<6; ++nf){
      int n = w*96 + nf*16 + lr;
      int j = n >> 7, nn = n & 127;
      const short* Bp = ZgtT + ((size_t)(j*49+t)*128 + nn)*128;
      #pragma unroll
      for (int ks=0; ks<4; ++ks){
        bf16x8 bf = *(const bf16x8*)(Bp + ks*32 + lk*8);
        acc[nf] = __builtin_amdgcn_mfma_f32_16x16x32_bf16(a[ks], bf, acc[nf], 0,0,0);
      }
    }
    #pragma unroll
    for (int nf=0; nf<6; ++nf){
      int n = w*96 + nf*16 + lr;
      int j = n >> 7, kk = n & 127;
      #pragma unroll
      for (int reg=0; reg<4; ++reg){
        int row = lk*4 + reg;
        preL[row*384 + n] = acc[nf][reg] +
            Agt[((size_t)t*3 + j)*98304 + (size_t)(rowbase + row)*128 + kk];
      }
    }
    __syncthreads();
    #pragma unroll
    for (int rr=0; rr<8; ++rr){
      int row = rh*8 + rr;
      float f  = sigm(preL[row*384 + k]);
      float gc = tanh_(preL[row*384 + 128 + k]);
      float og = sigm(preL[row*384 + 256 + k]);
      c[rr] = f*c[rr] + (1.0f - f)*gc;
      float gv = og * tanh_(c[rr]);
      if (t < 48){
        int byte = (row*256 + k*2) ^ ((row&7)<<4);
        *(short*)((char*)gA + byte) = f2bf(gv);
      } else {
        int r = rowbase + row;
        out[OUT_GT  + (size_t)r*128 + k] = gv;
        out[OUT_CGT + (size_t)r*128 + k] = c[rr];
      }
    }
    __syncthreads();
  }
}

// ---------------------------------------------------------------------------
extern "C" void kernel_launch(void* const* d_in, const int* in_sizes, int n_in,
                              void* d_out, int out_size, void* d_ws, size_t ws_size,
                              hipStream_t stream)
{
  (void)in_sizes; (void)n_in; (void)out_size; (void)ws_size;
  const float* h     = (const float*)d_in[0];
  const float* c_h   = (const float*)d_in[1];
  const float* p     = (const float*)d_in[2];
  const float* g_t   = (const float*)d_in[3];
  const float* c_g_t = (const float*)d_in[4];
  const float* g_s   = (const float*)d_in[5];
  const float* c_g_s = (const float*)d_in[6];
  const float* U     = (const float*)d_in[7];
  const float* Wt    = (const float*)d_in[8];
  const float* Ws    = (const float*)d_in[9];
  const float* Zt    = (const float*)d_in[10];
  const float* Zs    = (const float*)d_in[11];
  const float* bias  = (const float*)d_in[12];
  const float* Wgt   = (const float*)d_in[13];
  const float* Zgt   = (const float*)d_in[14];
  const float* bgt   = (const float*)d_in[15];
  const float* Wgs   = (const float*)d_in[16];
  const float* Zgs   = (const float*)d_in[17];
  const float* bgs   = (const float*)d_in[18];
  float* out = (float*)d_out;
  char* ws = (char*)d_ws;

  // workspace layout (bytes)
  const size_t WB_OFF  = 0;                       // bf16 [T][G][128][768]  86,704,128
  const size_t XC_OFF  = 86704128;                // bf16 [T][768][768]     57,802,752  (reused as Agt f32)
  const size_t PRE_OFF = XC_OFF + 57802752;       // bf16 [G][T][768][128]  86,704,128
  const size_t B2_OFF  = PRE_OFF + 86704128;      // f32  [G][T][32][128]    7,225,344
  const size_t HNB_OFF = B2_OFF + 7225344;        // bf16 [T][768][128]      9,633,792
  const size_t WGT_OFF = HNB_OFF + 9633792;       // bf16 [3][T][128][128]   4,816,896
  const size_t ZGT_OFF = WGT_OFF + 4816896;       // bf16                    4,816,896
  const size_t HM_OFF  = ZGT_OFF + 4816896;       // f32  [B][T][128]          802,816

  short* WBp   = (short*)(ws + WB_OFF);
  short* XCp   = (short*)(ws + XC_OFF);
  float* Agtp  = (float*)(ws + XC_OFF);           // alias: XC dead after main GEMM
  short* preBp = (short*)(ws + PRE_OFF);
  float* b2p   = (float*)(ws + B2_OFF);
  short* hnbp  = (short*)(ws + HNB_OFF);
  short* WgtTp = (short*)(ws + WGT_OFF);
  short* ZgtTp = (short*)(ws + ZGT_OFF);
  float* hmp   = (float*)(ws + HM_OFF);

  k_prep     <<<2940, 256, 0, stream>>>(U, Wt, Ws, Zt, Wgt, Zgt, WBp, WgtTp, ZgtTp);
  k_xc       <<<1568, 256, 0, stream>>>(h, p, g_t, XCp);
  k_bias2    <<< 441, 256, 0, stream>>>(g_s, Zs, bias, b2p);
  k_gemm_main<<<2646, 256, 0, stream>>>(XCp, WBp, b2p, preBp);
  k_stageb   <<<9408, 256, 0, stream>>>(preBp, c_h, c_g_t, c_g_s, out, hnbp);
  k_hm       <<<1568, 128, 0, stream>>>(out, hmp);
  k_gemm_agt <<< 882, 256, 0, stream>>>(hnbp, WgtTp, bgt, Agtp);
  k_gs       <<< 784, 256, 0, stream>>>(hmp, g_s, c_g_s, Wgs, Zgs, bgs, out);
  k_recur    <<<  48, 256, 0, stream>>>(Agtp, ZgtTp, g_t, c_g_t, out);
}

// Round 2
// 813.493 us; speedup vs baseline: 1.4940x; 1.4940x over previous
//
#include <hip/hip_runtime.h>
#include <cstdint>
#include <cstddef>

// B=32 T=49 N=24 H=128 G=9 ; R=B*N=768 ; concat K = 768
// d_out element offsets (fp32)
#define OUT_CH   4816896
#define OUT_GT   9633792
#define OUT_CGT  9732096
#define OUT_GS   9830400
#define OUT_CGS 10031104

typedef __attribute__((ext_vector_type(8))) short bf16x8;
typedef __attribute__((ext_vector_type(4))) float f32x4;

#define DEV static __device__ __forceinline__

DEV short f2bf(float f){
  union{float f; uint32_t u;} v; v.f=f;
  uint32_t r = v.u + 0x7fffu + ((v.u>>16)&1u);
  return (short)(r>>16);
}
DEV float bf2f(short s){
  union{uint32_t u; float f;} v; v.u = ((uint32_t)(uint16_t)s)<<16; return v.f;
}
DEV float sigm(float x){ return 1.0f/(1.0f + __expf(-x)); }
DEV float tanh_(float x){ return 2.0f/(1.0f + __expf(-2.0f*x)) - 1.0f; }

#define GLD16(gp, lp) __builtin_amdgcn_global_load_lds( \
    (const __attribute__((address_space(1))) unsigned int*)(gp), \
    (__attribute__((address_space(3))) unsigned int*)(lp), 16, 0, 0)

// ---------------------------------------------------------------------------
// 1. Weight transpose + bf16 cast.
//    blocks 0..2645: WB[t][g][kout 128][kin 768]  from U|Wt(3 chunks)|Ws|Zt
//    blocks 2646..2792: WgtT[j*49+t][128][128]
//    blocks 2793..2939: ZgtT[j*49+t][128][128]
__global__ __launch_bounds__(256) void k_prep(
    const float* __restrict__ U,  const float* __restrict__ Wt,
    const float* __restrict__ Ws, const float* __restrict__ Zt,
    const float* __restrict__ Wgt,const float* __restrict__ Zgt,
    short* __restrict__ WB, short* __restrict__ WgtT, short* __restrict__ ZgtT)
{
  __shared__ float tile[128*129];
  int bid = blockIdx.x, tid = threadIdx.x;
  const float* src; short* dst; int dstStride;
  if (bid < 2646){
    int c6 = bid % 6; int gt = bid / 6; int g = gt/49, t = gt%49;
    int gtH = g*49 + t;
    if (c6==0)      src = U  + (size_t)gtH*16384;
    else if (c6<=3) src = Wt + ((size_t)gtH*384 + (size_t)(c6-1)*128)*128;
    else if (c6==4) src = Ws + (size_t)gtH*16384;
    else            src = Zt + (size_t)gtH*16384;
    dst = WB + (size_t)(t*9+g)*128*768 + c6*128;
    dstStride = 768;
  } else if (bid < 2793){
    int i = bid - 2646;           // j*49+t
    src = Wgt + (size_t)i*16384;  dst = WgtT + (size_t)i*16384; dstStride = 128;
  } else {
    int i = bid - 2793;
    src = Zgt + (size_t)i*16384;  dst = ZgtT + (size_t)i*16384; dstStride = 128;
  }
  for (int it=0; it<64; ++it){               // load 128x128 fp32, padded LDS
    int idx = it*256 + tid;
    int r = idx >> 7, c = idx & 127;
    tile[r*129 + c] = src[idx];
  }
  __syncthreads();
  for (int it=0; it<32; ++it){               // write transposed bf16, short2
    int idx = it*256 + tid;                  // pair index
    int ko = idx >> 6;
    int ki = (idx & 63)*2;
    short2 v;
    v.x = f2bf(tile[(size_t)ki*129 + ko]);
    v.y = f2bf(tile[(size_t)(ki+1)*129 + ko]);
    *(short2*)&dst[(size_t)ko*dstStride + ki] = v;
  }
}

// ---------------------------------------------------------------------------
// 2. x_cat build: XC[t][r=b*24+n][768] bf16 = [h | h_{t-1} | p | h_{t+1} | x_s | g_t]
__global__ __launch_bounds__(256) void k_xc(
    const float* __restrict__ h, const float* __restrict__ p,
    const float* __restrict__ gt_in, short* __restrict__ XC)
{
  int bid = blockIdx.x, tid = threadIdx.x;
  int b = bid / 49, t = bid % 49;
  const size_t bt = ((size_t)b*49 + t)*24*128;
  for (int it=0; it<36; ++it){
    int idx = (it*256 + tid)*2;              // even element index, 0..18430
    int n = idx / 768; int kk = idx - n*768;
    int seg = kk >> 7; int k = kk & 127;
    size_t nk = (size_t)n*128 + k;
    float vx=0.f, vy=0.f;
    if (seg==0){ float2 u = *(const float2*)&h[bt + nk]; vx=u.x; vy=u.y; }
    else if (seg==1){ if (t>0){ float2 u = *(const float2*)&h[bt - 3072 + nk]; vx=u.x; vy=u.y; } }
    else if (seg==2){ float2 u = *(const float2*)&p[bt + nk]; vx=u.x; vy=u.y; }
    else if (seg==3){ if (t<48){ float2 u = *(const float2*)&h[bt + 3072 + nk]; vx=u.x; vy=u.y; } }
    else if (seg==4){
      if (n>0){ float2 u = *(const float2*)&h[bt + nk - 128]; vx+=u.x; vy+=u.y; }
      if (n<23){ float2 u = *(const float2*)&h[bt + nk + 128]; vx+=u.x; vy+=u.y; }
    } else {
      float2 u = *(const float2*)&gt_in[((size_t)b*24 + n)*128 + k]; vx=u.x; vy=u.y;
    }
    short2 s2; s2.x = f2bf(vx); s2.y = f2bf(vy);
    *(short2*)&XC[((size_t)t*768 + b*24 + n)*768 + kk] = s2;
  }
}

// ---------------------------------------------------------------------------
// 3. bias2[g][t][b][k] = b[g,t,k] + sum_h g_s[b,t,h]*Zs[g,t,h,k]
__global__ __launch_bounds__(256) void k_bias2(
    const float* __restrict__ gs_in, const float* __restrict__ Zs,
    const float* __restrict__ bvec, float* __restrict__ bias2)
{
  __shared__ float gsL[32*128];
  int bid = blockIdx.x, tid = threadIdx.x;
  int g = bid / 49, t = bid % 49;
  for (int i=0;i<16;++i){
    int idx = i*256 + tid; int bb = idx>>7, kk = idx&127;
    gsL[idx] = gs_in[((size_t)bb*49 + t)*128 + kk];
  }
  __syncthreads();
  int k = tid & 127, half = tid >> 7;
  float acc[16];
  #pragma unroll
  for (int i=0;i<16;++i) acc[i]=0.f;
  const float* Zb = Zs + (size_t)(g*49+t)*16384;
  for (int hc=0; hc<16; ++hc){
    float z[8];
    #pragma unroll
    for (int jj=0;jj<8;++jj) z[jj] = Zb[(size_t)(hc*8+jj)*128 + k];
    #pragma unroll
    for (int bb=0; bb<16; ++bb){
      const float* gp = &gsL[(half*16+bb)*128 + hc*8];
      #pragma unroll
      for (int jj=0;jj<8;++jj) acc[bb] += gp[jj]*z[jj];
    }
  }
  float bv = bvec[(size_t)(g*49+t)*128 + k];
  #pragma unroll
  for (int bb=0; bb<16; ++bb)
    bias2[((size_t)(g*49+t)*32 + half*16+bb)*128 + k] = acc[bb] + bv;
}

// ---------------------------------------------------------------------------
// 4. Main GEMM: pre[g][t][r][k] (bf16) = XC[t] (768x768) @ WB[t][g]^T + bias2
//    m97-style: 128x128 tile, BK=64, 4 waves, global_load_lds 16B.
//    bid remapped t-outer so 54 consecutive blocks share XC[t] in L2.
__global__ __launch_bounds__(256) void k_gemm_main(
    const short* __restrict__ XC, const short* __restrict__ WB,
    const float* __restrict__ bias2, short* __restrict__ preB)
{
  __shared__ short As[128*64];
  __shared__ short Bs[128*64];
  int bid = blockIdx.x, tid = threadIdx.x;
  int t = bid / 54; int rem = bid % 54; int g = rem / 6; int m = rem % 6;
  const int lane = tid & 63, w = tid >> 6;
  const int wm = w >> 1, wn = w & 1;
  const int lr = lane & 15, lk = lane >> 4;
  const short* Abase = XC + ((size_t)t*768 + m*128)*768;
  const short* Bbase = WB + (size_t)(t*9+g)*128*768;
  f32x4 acc[4][4] = {};
  for (int kt=0; kt<12; ++kt){
    int kofs = kt*64;
    #pragma unroll
    for (int it=0; it<4; ++it){
      int fb = it*4096 + tid*16;             // byte offset in 16KB tile
      int row = fb >> 7;
      int col = (fb & 127) >> 1;             // bf16 col 0..63
      GLD16(Abase + (size_t)row*768 + kofs + col, (char*)As + fb);
      GLD16(Bbase + (size_t)row*768 + kofs + col, (char*)Bs + fb);
    }
    __syncthreads();
    bf16x8 a[4][2], bb[4][2];
    #pragma unroll
    for (int mf=0; mf<4; ++mf)
      #pragma unroll
      for (int ks=0; ks<2; ++ks)
        a[mf][ks] = *(const bf16x8*)&As[(wm*64 + mf*16 + lr)*64 + ks*32 + lk*8];
    #pragma unroll
    for (int nf=0; nf<4; ++nf)
      #pragma unroll
      for (int ks=0; ks<2; ++ks)
        bb[nf][ks] = *(const bf16x8*)&Bs[(wn*64 + nf*16 + lr)*64 + ks*32 + lk*8];
    #pragma unroll
    for (int mf=0; mf<4; ++mf)
      #pragma unroll
      for (int nf=0; nf<4; ++nf)
        #pragma unroll
        for (int ks=0; ks<2; ++ks)
          acc[mf][nf] = __builtin_amdgcn_mfma_f32_16x16x32_bf16(a[mf][ks], bb[nf][ks], acc[mf][nf], 0,0,0);
    __syncthreads();
  }
  const size_t preBase = ((size_t)g*49 + t)*768*128;
  const size_t b2Base  = ((size_t)g*49 + t)*32*128;
  #pragma unroll
  for (int mf=0; mf<4; ++mf){
    #pragma unroll
    for (int nf=0; nf<4; ++nf){
      int kout = wn*64 + nf*16 + lr;
      #pragma unroll
      for (int reg=0; reg<4; ++reg){
        int gr = m*128 + wm*64 + mf*16 + lk*4 + reg;   // global row (b*24+n)
        int bb2 = (gr*2731) >> 16;                     // gr/24
        float v = acc[mf][nf][reg] + bias2[b2Base + (size_t)bb2*128 + kout];
        preB[preBase + (size_t)gr*128 + kout] = f2bf(v);
      }
    }
  }
}

// ---------------------------------------------------------------------------
// 5. Elementwise gate combine -> h_new, c_h_new (d_out) + hnb (bf16 copy)
__global__ __launch_bounds__(256) void k_stageb(
    const short* __restrict__ preB, const float* __restrict__ c_h,
    const float* __restrict__ c_gt, const float* __restrict__ c_gs,
    float* __restrict__ out, short* __restrict__ hnb)
{
  int bid = blockIdx.x, tid = threadIdx.x;
  int ng = bid % 6; int bt = bid / 6; int b = bt/49, t = bt%49;
  int nl = tid >> 6; int n = ng*4 + nl; int k = (tid & 63)*2;
  int r = b*24 + n;
  size_t btn = ((size_t)b*49 + t)*3072 + (size_t)n*128 + k;
  float pg[9][2];
  #pragma unroll
  for (int g=0; g<9; ++g){
    short2 s = *(const short2*)&preB[((size_t)g*49 + t)*98304 + (size_t)r*128 + k];
    pg[g][0] = bf2f(s.x); pg[g][1] = bf2f(s.y);
  }
  float cct[2], ctb[2]={0,0}, cta[2]={0,0}, cs[2]={0,0}, cgt[2], cgs[2];
  { float2 v = *(const float2*)&c_h[btn]; cct[0]=v.x; cct[1]=v.y; }
  if (t>0){ float2 v = *(const float2*)&c_h[btn - 3072]; ctb[0]=v.x; ctb[1]=v.y; }
  if (t<48){ float2 v = *(const float2*)&c_h[btn + 3072]; cta[0]=v.x; cta[1]=v.y; }
  if (n>0){ float2 v = *(const float2*)&c_h[btn - 128]; cs[0]+=v.x; cs[1]+=v.y; }
  if (n<23){ float2 v = *(const float2*)&c_h[btn + 128]; cs[0]+=v.x; cs[1]+=v.y; }
  { float2 v = *(const float2*)&c_gt[(size_t)r*128 + k]; cgt[0]=v.x; cgt[1]=v.y; }
  { float2 v = *(const float2*)&c_gs[((size_t)b*49 + t)*128 + k]; cgs[0]=v.x; cgs[1]=v.y; }
  float hn[2], cn[2];
  #pragma unroll
  for (int e=0; e<2; ++e){
    float gi = sigm(pg[0][e]), lt = sigm(pg[1][e]), ft = sigm(pg[2][e]), rt = sigm(pg[3][e]);
    float sg = sigm(pg[4][e]), gtg = sigm(pg[5][e]), gsg = sigm(pg[6][e]), o = sigm(pg[7][e]);
    float cc = tanh_(pg[8][e]);
    cn[e] = lt*ctb[e] + ft*cct[e] + rt*cta[e] + sg*cs[e] + gtg*cgt[e] + gsg*cgs[e] + gi*cc;
    hn[e] = o * tanh_(cn[e]);
  }
  float2 v1; v1.x = hn[0]; v1.y = hn[1];
  *(float2*)&out[btn] = v1;
  v1.x = cn[0]; v1.y = cn[1];
  *(float2*)&out[OUT_CH + btn] = v1;
  short2 s2; s2.x = f2bf(hn[0]); s2.y = f2bf(hn[1]);
  *(short2*)&hnb[((size_t)t*768 + r)*128 + k] = s2;
}

// ---------------------------------------------------------------------------
// 6. hm[b,t,k] = mean_n h_new
__global__ __launch_bounds__(128) void k_hm(const float* __restrict__ out, float* __restrict__ hm)
{
  int bid = blockIdx.x; int b = bid/49, t = bid%49; int k = threadIdx.x;
  float s = 0.f;
  for (int n=0;n<24;++n) s += out[((size_t)(b*49+t)*24 + n)*128 + k];
  hm[(size_t)(b*49+t)*128 + k] = s * (1.0f/24.0f);
}

// ---------------------------------------------------------------------------
// 7. Agt[t][j][r][k] = h_new[t] @ Wgt[j,t] + bgt[j,t]   (fp32 out)
//    bid remapped t-outer: 18 consecutive blocks share hnb[t].
__global__ __launch_bounds__(256) void k_gemm_agt(
    const short* __restrict__ hnb, const short* __restrict__ WgtT,
    const float* __restrict__ bgt, float* __restrict__ Agt)
{
  __shared__ short As[128*64];
  __shared__ short Bs[128*64];
  int bid = blockIdx.x, tid = threadIdx.x;
  int t = bid / 18; int rem = bid % 18; int j = rem / 6; int m = rem % 6;
  const int lane = tid & 63, w = tid >> 6;
  const int wm = w >> 1, wn = w & 1;
  const int lr = lane & 15, lk = lane >> 4;
  const short* Abase = hnb + ((size_t)t*768 + m*128)*128;
  const short* Bbase = WgtT + (size_t)(j*49+t)*16384;
  f32x4 acc[4][4] = {};
  for (int kt=0; kt<2; ++kt){
    int kofs = kt*64;
    #pragma unroll
    for (int it=0; it<4; ++it){
      int fb = it*4096 + tid*16;
      int row = fb >> 7;
      int col = (fb & 127) >> 1;
      GLD16(Abase + (size_t)row*128 + kofs + col, (char*)As + fb);
      GLD16(Bbase + (size_t)row*128 + kofs + col, (char*)Bs + fb);
    }
    __syncthreads();
    bf16x8 a[4][2], bb[4][2];
    #pragma unroll
    for (int mf=0; mf<4; ++mf)
      #pragma unroll
      for (int ks=0; ks<2; ++ks)
        a[mf][ks] = *(const bf16x8*)&As[(wm*64 + mf*16 + lr)*64 + ks*32 + lk*8];
    #pragma unroll
    for (int nf=0; nf<4; ++nf)
      #pragma unroll
      for (int ks=0; ks<2; ++ks)
        bb[nf][ks] = *(const bf16x8*)&Bs[(wn*64 + nf*16 + lr)*64 + ks*32 + lk*8];
    #pragma unroll
    for (int mf=0; mf<4; ++mf)
      #pragma unroll
      for (int nf=0; nf<4; ++nf)
        #pragma unroll
        for (int ks=0; ks<2; ++ks)
          acc[mf][nf] = __builtin_amdgcn_mfma_f32_16x16x32_bf16(a[mf][ks], bb[nf][ks], acc[mf][nf], 0,0,0);
    __syncthreads();
  }
  #pragma unroll
  for (int mf=0; mf<4; ++mf){
    #pragma unroll
    for (int nf=0; nf<4; ++nf){
      int kout = wn*64 + nf*16 + lr;
      #pragma unroll
      for (int reg=0; reg<4; ++reg){
        int gr = m*128 + wm*64 + mf*16 + lk*4 + reg;
        Agt[((size_t)t*3 + j)*98304 + (size_t)gr*128 + kout] =
            acc[mf][nf][reg] + bgt[(size_t)(j*49+t)*128 + kout];
      }
    }
  }
}

// ---------------------------------------------------------------------------
// 8. g_s path: 98 blocks (t x b-half); stage hm/gs for 16 b in LDS, read W/Z once.
__global__ __launch_bounds__(256) void k_gs(
    const float* __restrict__ hm, const float* __restrict__ gs_in,
    const float* __restrict__ cgs_in,
    const float* __restrict__ Wgs, const float* __restrict__ Zgs,
    const float* __restrict__ bgs, float* __restrict__ out)
{
  __shared__ float hmL[16][128], gsL[16][128];
  int bid = blockIdx.x, tid = threadIdx.x;
  int t = bid >> 1; int bh = bid & 1;
  for (int i=0;i<8;++i){
    int idx = i*256 + tid; int bb = idx>>7, kk = idx&127;
    int b = bh*16 + bb;
    hmL[bb][kk] = hm[((size_t)b*49 + t)*128 + kk];
    gsL[bb][kk] = gs_in[((size_t)b*49 + t)*128 + kk];
  }
  __syncthreads();
  int k = tid & 127; int half = tid >> 7;   // half -> 8 b each
  const float* W0 = Wgs + (size_t)t*16384;
  const float* W1 = Wgs + (size_t)(49+t)*16384;
  const float* W2 = Wgs + (size_t)(98+t)*16384;
  const float* Z0 = Zgs + (size_t)t*16384;
  const float* Z1 = Zgs + (size_t)(49+t)*16384;
  const float* Z2 = Zgs + (size_t)(98+t)*16384;
  float accf[8], accg[8], acco[8];
  #pragma unroll
  for (int i=0;i<8;++i){ accf[i]=0.f; accg[i]=0.f; acco[i]=0.f; }
  for (int h=0; h<128; ++h){
    float w0 = W0[(size_t)h*128+k], w1 = W1[(size_t)h*128+k], w2 = W2[(size_t)h*128+k];
    float z0 = Z0[(size_t)h*128+k], z1 = Z1[(size_t)h*128+k], z2 = Z2[(size_t)h*128+k];
    #pragma unroll
    for (int bb=0; bb<8; ++bb){
      float hv = hmL[half*8+bb][h], gv = gsL[half*8+bb][h];
      accf[bb] += hv*w0 + gv*z0;
      accg[bb] += hv*w1 + gv*z1;
      acco[bb] += hv*w2 + gv*z2;
    }
  }
  float b0 = bgs[(size_t)t*128 + k];
  float b1 = bgs[(size_t)(49+t)*128 + k];
  float b2 = bgs[(size_t)(98+t)*128 + k];
  #pragma unroll
  for (int bb=0; bb<8; ++bb){
    int b = bh*16 + half*8 + bb;
    float f  = sigm(accf[bb] + b0);
    float gc = tanh_(accg[bb] + b1);
    float og = sigm(acco[bb] + b2);
    float cg = cgs_in[((size_t)b*49 + t)*128 + k];
    float cn = f*cg + (1.0f-f)*gc;
    out[OUT_CGS + ((size_t)b*49+t)*128 + k] = cn;
    out[OUT_GS  + ((size_t)b*49+t)*128 + k] = og * tanh_(cn);
  }
}

// ---------------------------------------------------------------------------
// 9. g_t recurrence, rebuilt for latency:
//    48 blocks x 512 threads (8 waves). Wave w owns k-quarter w*16+lr for all
//    3 gates -> elementwise is lane-local (no preL exchange, 1 barrier/step).
//    Zgt(t+1)+Agt(t+1) prefetched into ping-pong registers at top of step t.
//    gA (g state, bf16, XOR-swizzled) double-buffered by step parity.
__global__ __launch_bounds__(512) void k_recur(
    const float* __restrict__ Agt, const short* __restrict__ ZgtT,
    const float* __restrict__ gt_in, const float* __restrict__ cgt_in,
    float* __restrict__ out)
{
  __shared__ short gA[2*16*128];    // two 4KB parity buffers
  int bid = blockIdx.x, tid = threadIdx.x;
  const int rowbase = bid*16;
  const int lane = tid & 63, w = tid >> 6;   // w 0..7
  const int lr = lane & 15, lk = lane >> 4;  // lk 0..3
  const int kq = w*16 + lr;                  // this lane's k column (0..127)

  // init c (4 rows per lane) + gA buffer 0
  float c[4];
  #pragma unroll
  for (int reg=0; reg<4; ++reg){
    int row = lk*4 + reg; int r = rowbase + row;
    c[reg] = cgt_in[(size_t)r*128 + kq];
    float gv = gt_in[(size_t)r*128 + kq];
    int byte = (row*256 + kq*2) ^ ((row&7)<<4);
    *(short*)((char*)gA + byte) = f2bf(gv);
  }

  bf16x8 Za[12], Zb[12];
  float  Aa[12], Ab[12];

#define LOADZA(Z, A, tt) { \
  _Pragma("unroll") \
  for (int j=0;j<3;++j){ \
    const short* Bp = ZgtT + (((size_t)j*49 + (size_t)(tt))*128 + (size_t)kq)*128 + lk*8; \
    _Pragma("unroll") \
    for (int ks=0;ks<4;++ks) Z[j*4+ks] = *(const bf16x8*)(Bp + ks*32); \
    _Pragma("unroll") \
    for (int reg=0;reg<4;++reg) \
      A[j*4+reg] = Agt[((size_t)(tt)*3 + j)*98304 + (size_t)(rowbase + lk*4 + reg)*128 + kq]; \
  } }

#define RSTEP(Z, A, tt, p) { \
  bf16x8 af[4]; \
  _Pragma("unroll") \
  for (int ks=0;ks<4;++ks){ \
    int byte = ((lr*256 + ks*64 + lk*16) ^ ((lr&7)<<4)) + (p)*4096; \
    af[ks] = *(const bf16x8*)((const char*)gA + byte); \
  } \
  f32x4 acc0 = {}, acc1 = {}, acc2 = {}; \
  _Pragma("unroll") \
  for (int ks=0;ks<4;++ks){ \
    acc0 = __builtin_amdgcn_mfma_f32_16x16x32_bf16(af[ks], Z[0*4+ks], acc0, 0,0,0); \
    acc1 = __builtin_amdgcn_mfma_f32_16x16x32_bf16(af[ks], Z[1*4+ks], acc1, 0,0,0); \
    acc2 = __builtin_amdgcn_mfma_f32_16x16x32_bf16(af[ks], Z[2*4+ks], acc2, 0,0,0); \
  } \
  _Pragma("unroll") \
  for (int reg=0;reg<4;++reg){ \
    float f  = sigm(acc0[reg] + A[0*4+reg]); \
    float gc = tanh_(acc1[reg] + A[1*4+reg]); \
    float og = sigm(acc2[reg] + A[2*4+reg]); \
    c[reg] = f*c[reg] + (1.0f - f)*gc; \
    float gv = og * tanh_(c[reg]); \
    if ((tt) < 48){ \
      int row = lk*4 + reg; \
      int byte = ((row*256 + kq*2) ^ ((row&7)<<4)) + (((p)^1))*4096; \
      *(short*)((char*)gA + byte) = f2bf(gv); \
    } else { \
      int r = rowbase + lk*4 + reg; \
      out[OUT_GT  + (size_t)r*128 + kq] = gv; \
      out[OUT_CGT + (size_t)r*128 + kq] = c[reg]; \
    } \
  } \
  __syncthreads(); }

  LOADZA(Za, Aa, 0);
  __syncthreads();                 // gA init visible

  for (int t=0; t<48; t+=2){
    LOADZA(Zb, Ab, t+1);
    RSTEP(Za, Aa, t, 0);
    { int t2 = (t+2 <= 48) ? t+2 : 48;
      LOADZA(Za, Aa, t2); }
    RSTEP(Zb, Ab, t+1, 1);
  }
  RSTEP(Za, Aa, 48, 0);

#undef LOADZA
#undef RSTEP
}

// ---------------------------------------------------------------------------
extern "C" void kernel_launch(void* const* d_in, const int* in_sizes, int n_in,
                              void* d_out, int out_size, void* d_ws, size_t ws_size,
                              hipStream_t stream)
{
  (void)in_sizes; (void)n_in; (void)out_size; (void)ws_size;
  const float* h     = (const float*)d_in[0];
  const float* c_h   = (const float*)d_in[1];
  const float* p     = (const float*)d_in[2];
  const float* g_t   = (const float*)d_in[3];
  const float* c_g_t = (const float*)d_in[4];
  const float* g_s   = (const float*)d_in[5];
  const float* c_g_s = (const float*)d_in[6];
  const float* U     = (const float*)d_in[7];
  const float* Wt    = (const float*)d_in[8];
  const float* Ws    = (const float*)d_in[9];
  const float* Zt    = (const float*)d_in[10];
  const float* Zs    = (const float*)d_in[11];
  const float* bias  = (const float*)d_in[12];
  const float* Wgt   = (const float*)d_in[13];
  const float* Zgt   = (const float*)d_in[14];
  const float* bgt   = (const float*)d_in[15];
  const float* Wgs   = (const float*)d_in[16];
  const float* Zgs   = (const float*)d_in[17];
  const float* bgs   = (const float*)d_in[18];
  float* out = (float*)d_out;
  char* ws = (char*)d_ws;

  // workspace layout (bytes)
  const size_t WB_OFF  = 0;                       // bf16 [T][G][128][768]  86,704,128
  const size_t XC_OFF  = 86704128;                // bf16 [T][768][768]     57,802,752  (reused as Agt f32)
  const size_t PRE_OFF = XC_OFF + 57802752;       // bf16 [G][T][768][128]  86,704,128
  const size_t B2_OFF  = PRE_OFF + 86704128;      // f32  [G][T][32][128]    7,225,344
  const size_t HNB_OFF = B2_OFF + 7225344;        // bf16 [T][768][128]      9,633,792
  const size_t WGT_OFF = HNB_OFF + 9633792;       // bf16 [3][T][128][128]   4,816,896
  const size_t ZGT_OFF = WGT_OFF + 4816896;       // bf16                    4,816,896
  const size_t HM_OFF  = ZGT_OFF + 4816896;       // f32  [B][T][128]          802,816

  short* WBp   = (short*)(ws + WB_OFF);
  short* XCp   = (short*)(ws + XC_OFF);
  float* Agtp  = (float*)(ws + XC_OFF);           // alias: XC dead after main GEMM
  short* preBp = (short*)(ws + PRE_OFF);
  float* b2p   = (float*)(ws + B2_OFF);
  short* hnbp  = (short*)(ws + HNB_OFF);
  short* WgtTp = (short*)(ws + WGT_OFF);
  short* ZgtTp = (short*)(ws + ZGT_OFF);
  float* hmp   = (float*)(ws + HM_OFF);

  k_prep     <<<2940, 256, 0, stream>>>(U, Wt, Ws, Zt, Wgt, Zgt, WBp, WgtTp, ZgtTp);
  k_xc       <<<1568, 256, 0, stream>>>(h, p, g_t, XCp);
  k_bias2    <<< 441, 256, 0, stream>>>(g_s, Zs, bias, b2p);
  k_gemm_main<<<2646, 256, 0, stream>>>(XCp, WBp, b2p, preBp);
  k_stageb   <<<9408, 256, 0, stream>>>(preBp, c_h, c_g_t, c_g_s, out, hnbp);
  k_hm       <<<1568, 128, 0, stream>>>(out, hmp);
  k_gemm_agt <<< 882, 256, 0, stream>>>(hnbp, WgtTp, bgt, Agtp);
  k_gs       <<<  98, 256, 0, stream>>>(hmp, g_s, c_g_s, Wgs, Zgs, bgs, out);
  k_recur    <<<  48, 512, 0, stream>>>(Agtp, ZgtTp, g_t, c_g_t, out);
}